// Round 2
// baseline (71.897 us; speedup 1.0000x reference)
//
#include <hip/hip_runtime.h>

// HistogramLoss_2channel: sparse soft-histogram formulation.
// Triangle half-width 1/255 < bin spacing 1/128, so each pixel value hits
// <=2 of 256 bins; the per-pixel 2D outer product has <=4 nonzeros.
// hist2d = scatter of <=4 atomicAdds per pixel into a 256x256 fp32 histogram.
//
// NOTE: hipMemsetAsync silently fails to enter the captured graph here
// (post-timing divergence showed hist accumulating across ~213 replays),
// so d_ws is zeroed with a kernel instead.

#define NPIX 65536   // 256*256 pixels
#define BINS 256

__global__ void zero_kernel(float4* __restrict__ p) {
    int i = blockIdx.x * blockDim.x + threadIdx.x;   // 65536 threads
    p[i] = make_float4(0.f, 0.f, 0.f, 0.f);
}

__global__ void hist_kernel(const float* __restrict__ inp,
                            const float* __restrict__ ref,
                            float* __restrict__ hist) {
    int gid = blockIdx.x * blockDim.x + threadIdx.x;   // 4*65536 threads
    int pix = gid & (NPIX - 1);
    int bb  = (gid >> 16) & 1;   // batch
    int im  = gid >> 17;         // 0 = inp, 1 = ref
    const float* src = im ? ref : inp;
    // layout [B,2,H,W]: channel 0 -> ha (r dim), channel 1 -> hb (j dim)
    float x0 = src[bb * (2 * NPIX) + pix];
    float x1 = src[bb * (2 * NPIX) + NPIX + pix];
    float* h = hist + (im * 2 + bb) * (BINS * BINS);

    // reference: u=(x+1)/2, a1 = u + 1 - k/128, w = relu(1 - |a1|*255)
    //          = relu(1 - |t - k| * (255/128)) with t = 64x + 192
    float t0 = 64.f * x0 + 192.f;
    float t1 = 64.f * x1 + 192.f;
    int k0 = (int)floorf(t0);
    int k1 = (int)floorf(t1);

    float wr[2]; int ir[2]; int nr = 0;
    #pragma unroll
    for (int d = 0; d < 2; ++d) {
        int k = k0 + d;
        float w = 1.f - fabsf(t0 - (float)k) * 1.9921875f;  // 255/128 exact
        if (w > 0.f && k >= 0 && k < BINS) { wr[nr] = w; ir[nr] = k; ++nr; }
    }
    float wj[2]; int ij[2]; int nj = 0;
    #pragma unroll
    for (int d = 0; d < 2; ++d) {
        int k = k1 + d;
        float w = 1.f - fabsf(t1 - (float)k) * 1.9921875f;
        if (w > 0.f && k >= 0 && k < BINS) { wj[nj] = w; ij[nj] = k; ++nj; }
    }
    for (int a = 0; a < nj; ++a)
        for (int b = 0; b < nr; ++b)
            atomicAdd(&h[ij[a] * BINS + ir[b]], wj[a] * wr[b]);
}

__global__ void loss_kernel(const float* __restrict__ hist,
                            float* __restrict__ out) {
    int idx = blockIdx.x * blockDim.x + threadIdx.x;   // 2*65536
    int bb = idx >> 16;
    int jr = idx & (NPIX - 1);
    const float inv = 1.f / 65536.f;                   // 1/(H*W), exact pow2
    float h1 = hist[(0 * 2 + bb) * (BINS * BINS) + jr] * inv;
    float h2 = hist[(1 * 2 + bb) * (BINS * BINS) + jr] * inv;
    float mann = fabsf(h1 - h2);
    // Huber: mann < delta -> 0.5*mann^2/delta ; else mann - 0.5*delta
    float loss = (mann < 0.01f) ? (50.f * mann * mann) : (mann - 0.005f);
    out[idx] = loss;
}

extern "C" void kernel_launch(void* const* d_in, const int* in_sizes, int n_in,
                              void* d_out, int out_size, void* d_ws, size_t ws_size,
                              hipStream_t stream) {
    const float* inp = (const float*)d_in[0];
    const float* ref = (const float*)d_in[1];
    float* hist = (float*)d_ws;                // 4 * 65536 floats = 1 MiB
    float* out  = (float*)d_out;               // 2*1*256*256 = 131072 floats

    zero_kernel<<<(4 * NPIX / 4) / 256, 256, 0, stream>>>((float4*)hist);
    hist_kernel<<<(4 * NPIX) / 256, 256, 0, stream>>>(inp, ref, hist);
    loss_kernel<<<(2 * NPIX) / 256, 256, 0, stream>>>(hist, out);
}